// Round 1
// baseline (364.351 us; speedup 1.0000x reference)
//
#include <hip/hip_runtime.h>

// Problem constants
#define B_ 8
#define H_ 8
#define S_ 4096
#define D_ 64
#define DM_ 768
#define NSTORE 4094            // S-2
#define DENOM 32752.0f         // B*(S-2)

typedef short bfrag_t __attribute__((ext_vector_type(8)));   // 8 bf16 (A/B frag)
typedef float f32x4_t __attribute__((ext_vector_type(4)));   // C/D frag

__device__ inline unsigned short f2bf(float x) {
    unsigned int u = __float_as_uint(x);
    unsigned int r = (u + 0x7fffu + ((u >> 16) & 1u)) >> 16;  // RNE
    return (unsigned short)r;
}

// ---------------------------------------------------------------------------
// Kernel 1: per-head Gram matrices G (normalized) and U (raw QV), fp32 vector.
// grid (split=8, h=8, b=8), block 256. Partials merged via atomicAdd.
// ---------------------------------------------------------------------------
__global__ __launch_bounds__(256) void gram_kernel(
    const float* __restrict__ Q, const float* __restrict__ V,
    float* __restrict__ gG, float* __restrict__ gU) {
    const int split = blockIdx.x, h = blockIdx.y, b = blockIdx.z;
    const int t = threadIdx.x;
    __shared__ float Qs[64][64];
    __shared__ float Vs[64][64];
    __shared__ float nrm[64][4];
    __shared__ float scale[64];
    const float* Qbh = Q + ((size_t)(b * H_ + h)) * S_ * D_;
    const float* Vbh = V + ((size_t)(b * H_ + h)) * S_ * D_;
    const int r0 = split * 512;
    const int pi = (t >> 4) << 2;   // 0..60 step 4 (p block)
    const int qj = (t & 15) << 2;   // 0..60 step 4 (q block)
    float accG[4][4] = {{0.f}};
    float accU[4][4] = {{0.f}};

    for (int tile = 0; tile < 8; ++tile) {
        const int rbase = r0 + tile * 64;
        // stage 64x64 Q and V tiles (V shifted by +2)
        #pragma unroll
        for (int i = 0; i < 4; ++i) {
            int f = i * 256 + t;            // 0..1023
            int row = f >> 4, c4 = f & 15;
            int r = rbase + row;
            float4 q4 = make_float4(0.f, 0.f, 0.f, 0.f);
            float4 v4 = make_float4(0.f, 0.f, 0.f, 0.f);
            if (r < NSTORE) {
                q4 = *(const float4*)(Qbh + (size_t)r * D_ + c4 * 4);
                v4 = *(const float4*)(Vbh + (size_t)(r + 2) * D_ + c4 * 4);
            }
            *(float4*)(&Qs[row][c4 * 4]) = q4;
            *(float4*)(&Vs[row][c4 * 4]) = v4;
        }
        __syncthreads();
        // row norms (clip(norm,1e-8)^2 == max(n2,1e-16))
        {
            int row = t & 63, part = t >> 6;
            float s = 0.f;
            #pragma unroll
            for (int c = 0; c < 16; ++c) { float x = Qs[row][part * 16 + c]; s += x * x; }
            nrm[row][part] = s;
        }
        __syncthreads();
        if (t < 64) {
            float n2 = nrm[t][0] + nrm[t][1] + nrm[t][2] + nrm[t][3];
            scale[t] = 1.0f / fmaxf(n2, 1e-16f);
        }
        __syncthreads();
        // 4x4 outer-product micro-kernel per thread
        for (int r = 0; r < 64; ++r) {
            float4 ap = *(const float4*)(&Qs[r][pi]);
            float4 aq = *(const float4*)(&Qs[r][qj]);
            float4 vq = *(const float4*)(&Vs[r][qj]);
            float sc = scale[r];
            float app[4] = {ap.x, ap.y, ap.z, ap.w};
            float sap[4] = {ap.x * sc, ap.y * sc, ap.z * sc, ap.w * sc};
            float aqq[4] = {aq.x, aq.y, aq.z, aq.w};
            float vqq[4] = {vq.x, vq.y, vq.z, vq.w};
            #pragma unroll
            for (int i = 0; i < 4; ++i)
                #pragma unroll
                for (int j = 0; j < 4; ++j) {
                    accG[i][j] += sap[i] * aqq[j];
                    accU[i][j] += app[i] * vqq[j];
                }
        }
        __syncthreads();
    }
    float* gGh = gG + h * 4096;
    float* gUh = gU + h * 4096;
    #pragma unroll
    for (int i = 0; i < 4; ++i)
        #pragma unroll
        for (int j = 0; j < 4; ++j) {
            atomicAdd(&gGh[(pi + i) * 64 + (qj + j)], accG[i][j]);
            atomicAdd(&gUh[(pi + i) * 64 + (qj + j)], accU[i][j]);
        }
}

// ---------------------------------------------------------------------------
// Kernel 2: T_new[h] = 0.99*(trace - G@trace/denom) + 0.1*U/denom. grid=H.
// ---------------------------------------------------------------------------
__global__ __launch_bounds__(256) void trace_kernel(
    const float* __restrict__ gG, const float* __restrict__ gU,
    const float* __restrict__ trace, float* __restrict__ Tnew) {
    const int h = blockIdx.x, t = threadIdx.x;
    __shared__ float Gs[64][64];
    __shared__ float Ts[64][64];
    const float* Gh = gG + h * 4096;
    const float* Uh = gU + h * 4096;
    const float* Th = trace + h * 4096;
    float* To = Tnew + h * 4096;
    for (int k = 0; k < 16; ++k) {
        int e = k * 256 + t;
        Gs[e >> 6][e & 63] = Gh[e];
        Ts[e >> 6][e & 63] = Th[e];
    }
    __syncthreads();
    const float inv_denom = 1.0f / DENOM;
    for (int k = 0; k < 16; ++k) {
        int e = k * 256 + t;
        int p = e >> 6, q = e & 63;
        float dot = 0.f;
        #pragma unroll
        for (int r = 0; r < 64; ++r) dot += Gs[p][r] * Ts[r][q];
        To[e] = 0.99f * (Ts[p][q] - dot * inv_denom) + 0.1f * (Uh[e] * inv_denom);
    }
}

// ---------------------------------------------------------------------------
// Kernel 3: WcT[n][h*64+p] = sum_q T_new[h][p][q] * W_out[n][h*64+q], bf16 out.
// grid (nc=6, h=8), block 256.
// ---------------------------------------------------------------------------
__global__ __launch_bounds__(256) void wc_kernel(
    const float* __restrict__ Tnew, const float* __restrict__ Wout,
    unsigned short* __restrict__ WcT) {
    const int nc = blockIdx.x, h = blockIdx.y, t = threadIdx.x;
    __shared__ float TsT[64][64];  // [q][p]
    __shared__ float Ws[4][64];
    const float* Th = Tnew + h * 4096;
    for (int k = 0; k < 16; ++k) {
        int e = k * 256 + t;
        TsT[e & 63][e >> 6] = Th[e];   // transposed stage
    }
    __syncthreads();
    const int p = t & 63, sub = t >> 6;
    for (int i = 0; i < 32; ++i) {
        int n = nc * 128 + i * 4 + sub;
        Ws[sub][p] = Wout[(size_t)n * 512 + h * 64 + p];  // p used as q here
        __syncthreads();
        float acc = 0.f;
        #pragma unroll
        for (int q = 0; q < 64; ++q) acc += TsT[q][p] * Ws[sub][q];
        WcT[(size_t)n * 512 + h * 64 + p] = f2bf(acc);
        __syncthreads();
    }
}

// ---------------------------------------------------------------------------
// Kernel 4: out(32768x768) = Q_addr(32768x512) @ Wc(512x768), bf16 MFMA.
// 128x128 block tile, BK=32, 4 waves, 4x4 16x16x32 MFMAs per wave.
// grid (mTile=256, nTile=6), block 256.
// ---------------------------------------------------------------------------
__global__ __launch_bounds__(256, 2) void matmul_kernel(
    const float* __restrict__ Q, const unsigned short* __restrict__ WcT,
    float* __restrict__ out) {
    const int mTile = blockIdx.x;  // 0..255
    const int nTile = blockIdx.y;  // 0..5
    const int t = threadIdx.x;
    const int wave = t >> 6, lane = t & 63;
    const int wm = wave >> 1, wn = wave & 1;
    const int quad = lane >> 4, l15 = lane & 15;
    __shared__ __align__(16) unsigned short As[128][40];  // pad 32->40 (bank spread)
    __shared__ __align__(16) unsigned short Bs[128][40];  // BsT: [n][k]
    const int b = mTile >> 5;
    const int s0 = (mTile & 31) * 128;
    const int nBase = nTile * 128;
    f32x4_t acc[4][4] = {};

    for (int kt = 0; kt < 16; ++kt) {
        const int h = kt >> 1, d0 = (kt & 1) * 32;
        const float* Qb = Q + ((size_t)(b * H_ + h)) * S_ * D_;
        // stage A tile: 128 rows x 32 cols (fp32 -> bf16), shift-by-1, s==0 -> 0
        #pragma unroll
        for (int i = 0; i < 4; ++i) {
            int f = i * 256 + t;         // 0..1023
            int row = f >> 3, c4 = f & 7;
            int s = s0 + row;
            float4 q4 = make_float4(0.f, 0.f, 0.f, 0.f);
            if (s > 0) q4 = *(const float4*)(Qb + (size_t)(s - 1) * D_ + d0 + c4 * 4);
            ushort4 u;
            u.x = f2bf(q4.x); u.y = f2bf(q4.y); u.z = f2bf(q4.z); u.w = f2bf(q4.w);
            *(ushort4*)(&As[row][c4 * 4]) = u;
        }
        // stage B tile (already bf16, n-major): 128 rows x 32 k
        #pragma unroll
        for (int i = 0; i < 2; ++i) {
            int f = i * 256 + t;         // 0..511
            int n = f >> 2, c8 = f & 3;
            uint4 w = *(const uint4*)(WcT + ((size_t)(nBase + n)) * 512 + kt * 32 + c8 * 8);
            *(uint4*)(&Bs[n][c8 * 8]) = w;
        }
        __syncthreads();
        bfrag_t af[4], bf[4];
        #pragma unroll
        for (int i = 0; i < 4; ++i) {
            int row = wm * 64 + i * 16 + l15;
            af[i] = *(const bfrag_t*)(&As[row][quad * 8]);
        }
        #pragma unroll
        for (int j = 0; j < 4; ++j) {
            int row = wn * 64 + j * 16 + l15;
            bf[j] = *(const bfrag_t*)(&Bs[row][quad * 8]);
        }
        #pragma unroll
        for (int i = 0; i < 4; ++i)
            #pragma unroll
            for (int j = 0; j < 4; ++j)
                acc[i][j] = __builtin_amdgcn_mfma_f32_16x16x32_bf16(af[i], bf[j], acc[i][j], 0, 0, 0);
        __syncthreads();
    }
    // epilogue: C layout col=lane&15, row=quad*4+reg
    const size_t mBase = (size_t)mTile * 128;
    #pragma unroll
    for (int i = 0; i < 4; ++i) {
        int mrow = wm * 64 + i * 16 + quad * 4;
        #pragma unroll
        for (int j = 0; j < 4; ++j) {
            int n = nBase + wn * 64 + j * 16 + l15;
            #pragma unroll
            for (int r = 0; r < 4; ++r)
                out[(mBase + mrow + r) * DM_ + n] = acc[i][j][r];
        }
    }
}

// ---------------------------------------------------------------------------
extern "C" void kernel_launch(void* const* d_in, const int* in_sizes, int n_in,
                              void* d_out, int out_size, void* d_ws, size_t ws_size,
                              hipStream_t stream) {
    const float* Q     = (const float*)d_in[0];
    const float* V     = (const float*)d_in[1];
    const float* trace = (const float*)d_in[2];
    const float* Wout  = (const float*)d_in[3];
    float* out = (float*)d_out;

    float* gG   = (float*)d_ws;              // 32768 floats
    float* gU   = gG + 32768;                // 32768 floats
    float* Tnew = gU + 32768;                // 32768 floats
    unsigned short* WcT = (unsigned short*)(Tnew + 32768);  // 768*512 bf16

    hipMemsetAsync(d_ws, 0, 2 * 32768 * sizeof(float), stream);
    gram_kernel<<<dim3(8, 8, 8), 256, 0, stream>>>(Q, V, gG, gU);
    trace_kernel<<<8, 256, 0, stream>>>(gG, gU, trace, Tnew);
    wc_kernel<<<dim3(6, 8), 256, 0, stream>>>(Tnew, Wout, WcT);
    matmul_kernel<<<dim3(256, 6), 256, 0, stream>>>(Q, WcT, out);
}

// Round 2
// 306.304 us; speedup vs baseline: 1.1895x; 1.1895x over previous
//
#include <hip/hip_runtime.h>

#define B_ 8
#define H_ 8
#define S_ 4096
#define D_ 64
#define DM_ 768
#define NSTORE 4094            // S-2
#define DENOM 32752.0f         // B*(S-2)

typedef short bfrag_t __attribute__((ext_vector_type(8)));   // 8 bf16 (A/B frag)
typedef float f32x4_t __attribute__((ext_vector_type(4)));   // C/D frag
typedef unsigned short us8_t __attribute__((ext_vector_type(8)));

__device__ inline unsigned short f2bf(float x) {
    unsigned int u = __float_as_uint(x);
    unsigned int r = (u + 0x7fffu + ((u >> 16) & 1u)) >> 16;  // RNE
    return (unsigned short)r;
}

// ---------------------------------------------------------------------------
// Kernel 1 (MFMA): per-head G = Qn^T Q, U = Q^T V  (64x64, K=rows).
// grid (split=8, h=8, b=8), block 256 (4 waves). Each block: 512 rows in 8
// tiles of 64. fp32 coalesced stage -> LDS transpose to bf16 -> MFMA.
// Also emits bf16 copy of Q (Qbf) for the output GEMM.
// ---------------------------------------------------------------------------
__global__ __launch_bounds__(256, 2) void gram_kernel(
    const float* __restrict__ Q, const float* __restrict__ V,
    float* __restrict__ gG, float* __restrict__ gU,
    unsigned short* __restrict__ Qbf, int writeQbf) {
    const int split = blockIdx.x, h = blockIdx.y, b = blockIdx.z;
    const int t = threadIdx.x;
    const int wave = t >> 6, lane = t & 63;
    const int quad = lane >> 4, l15 = lane & 15;
    __shared__ float Qs[64][68];                       // stride 68: uniform banks
    __shared__ float Vs[64][68];
    __shared__ float scale[64];
    __shared__ __align__(16) unsigned short QT[64][72];  // [p][k], 144B rows
    __shared__ __align__(16) unsigned short QnT[64][72];
    __shared__ __align__(16) unsigned short VT[64][72];

    const size_t bh = (size_t)(b * H_ + h);
    const float* Qbh = Q + bh * S_ * D_;
    const float* Vbh = V + bh * S_ * D_;
    unsigned short* Qbfbh = Qbf + bh * S_ * D_;

    f32x4_t accG[4] = {}, accU[4] = {};
    const int r0 = split * 512;

    for (int tile = 0; tile < 8; ++tile) {
        const int rbase = r0 + tile * 64;
        // ---- Phase A: coalesced fp32 stage + row norms + Qbf emit ----
        #pragma unroll
        for (int i = 0; i < 4; ++i) {
            int f = i * 256 + t;
            int row = f >> 4, c4 = f & 15;
            int r = rbase + row;
            float4 q4 = *(const float4*)(Qbh + (size_t)r * D_ + c4 * 4);  // r<4096 always
            if (writeQbf) {
                ushort4 u;
                u.x = f2bf(q4.x); u.y = f2bf(q4.y); u.z = f2bf(q4.z); u.w = f2bf(q4.w);
                *(ushort4*)(Qbfbh + (size_t)r * D_ + c4 * 4) = u;
            }
            float4 v4 = make_float4(0.f, 0.f, 0.f, 0.f);
            if (r < NSTORE) {
                v4 = *(const float4*)(Vbh + (size_t)(r + 2) * D_ + c4 * 4);
            } else {
                q4 = make_float4(0.f, 0.f, 0.f, 0.f);   // mask store-range for gram
            }
            *(float4*)(&Qs[row][c4 * 4]) = q4;
            *(float4*)(&Vs[row][c4 * 4]) = v4;
            // row sumsq across the 16 lanes sharing this row
            float ss = q4.x * q4.x + q4.y * q4.y + q4.z * q4.z + q4.w * q4.w;
            ss += __shfl_xor(ss, 1);
            ss += __shfl_xor(ss, 2);
            ss += __shfl_xor(ss, 4);
            ss += __shfl_xor(ss, 8);
            if ((t & 15) == 0) scale[row] = 1.0f / fmaxf(ss, 1e-16f);
        }
        __syncthreads();
        // ---- Phase C: transpose to bf16 (QT, QnT, VT) ----
        #pragma unroll
        for (int it = 0; it < 2; ++it) {
            int idx = it * 256 + t;
            int p = idx & 63, oct = idx >> 6;          // oct wave-uniform
            us8_t qt, qn, vt;
            #pragma unroll
            for (int j = 0; j < 8; ++j) {
                int r = oct * 8 + j;
                float s = scale[r];
                float q = Qs[r][p];
                float v = Vs[r][p];
                qt[j] = f2bf(q);
                qn[j] = f2bf(q * s);
                vt[j] = f2bf(v);
            }
            *(us8_t*)(&QT[p][oct * 8])  = qt;
            *(us8_t*)(&QnT[p][oct * 8]) = qn;
            *(us8_t*)(&VT[p][oct * 8])  = vt;
        }
        __syncthreads();
        // ---- Phase D: MFMA accumulate. Wave w owns p-strip [w*16, w*16+16) ----
        #pragma unroll
        for (int c = 0; c < 2; ++c) {
            int k0 = c * 32 + quad * 8;
            bfrag_t ag = *(const bfrag_t*)(&QnT[wave * 16 + l15][k0]);
            bfrag_t au = *(const bfrag_t*)(&QT[wave * 16 + l15][k0]);
            #pragma unroll
            for (int j = 0; j < 4; ++j) {
                bfrag_t bq = *(const bfrag_t*)(&QT[j * 16 + l15][k0]);
                bfrag_t bv = *(const bfrag_t*)(&VT[j * 16 + l15][k0]);
                accG[j] = __builtin_amdgcn_mfma_f32_16x16x32_bf16(ag, bq, accG[j], 0, 0, 0);
                accU[j] = __builtin_amdgcn_mfma_f32_16x16x32_bf16(au, bv, accU[j], 0, 0, 0);
            }
        }
        __syncthreads();
    }
    // ---- Epilogue: C layout col=lane&15, row=quad*4+reg ----
    float* gGh = gG + h * 4096;
    float* gUh = gU + h * 4096;
    #pragma unroll
    for (int j = 0; j < 4; ++j) {
        int col = j * 16 + l15;
        #pragma unroll
        for (int r = 0; r < 4; ++r) {
            int row = wave * 16 + quad * 4 + r;
            atomicAdd(&gGh[row * 64 + col], accG[j][r]);
            atomicAdd(&gUh[row * 64 + col], accU[j][r]);
        }
    }
}

// ---------------------------------------------------------------------------
// Kernel 2: T_new[h] = 0.99*(trace - G@trace/denom) + 0.1*U/denom. grid=H.
// ---------------------------------------------------------------------------
__global__ __launch_bounds__(256) void trace_kernel(
    const float* __restrict__ gG, const float* __restrict__ gU,
    const float* __restrict__ trace, float* __restrict__ Tnew) {
    const int h = blockIdx.x, t = threadIdx.x;
    __shared__ float Gs[64][64];
    __shared__ float Ts[64][64];
    const float* Gh = gG + h * 4096;
    const float* Uh = gU + h * 4096;
    const float* Th = trace + h * 4096;
    float* To = Tnew + h * 4096;
    for (int k = 0; k < 16; ++k) {
        int e = k * 256 + t;
        Gs[e >> 6][e & 63] = Gh[e];
        Ts[e >> 6][e & 63] = Th[e];
    }
    __syncthreads();
    const float inv_denom = 1.0f / DENOM;
    for (int k = 0; k < 16; ++k) {
        int e = k * 256 + t;
        int p = e >> 6, q = e & 63;
        float dot = 0.f;
        #pragma unroll
        for (int r = 0; r < 64; ++r) dot += Gs[p][r] * Ts[r][q];
        To[e] = 0.99f * (Ts[p][q] - dot * inv_denom) + 0.1f * (Uh[e] * inv_denom);
    }
}

// ---------------------------------------------------------------------------
// Kernel 3: WcT[n][h*64+p] = sum_q T_new[h][p][q] * W_out[n][h*64+q], bf16 out.
// grid (nc=6, h=8), block 256.
// ---------------------------------------------------------------------------
__global__ __launch_bounds__(256) void wc_kernel(
    const float* __restrict__ Tnew, const float* __restrict__ Wout,
    unsigned short* __restrict__ WcT) {
    const int nc = blockIdx.x, h = blockIdx.y, t = threadIdx.x;
    __shared__ float TsT[64][64];  // [q][p]
    __shared__ float Ws[4][64];
    const float* Th = Tnew + h * 4096;
    for (int k = 0; k < 16; ++k) {
        int e = k * 256 + t;
        TsT[e & 63][e >> 6] = Th[e];
    }
    __syncthreads();
    const int p = t & 63, sub = t >> 6;
    for (int i = 0; i < 32; ++i) {
        int n = nc * 128 + i * 4 + sub;
        Ws[sub][p] = Wout[(size_t)n * 512 + h * 64 + p];
        __syncthreads();
        float acc = 0.f;
        #pragma unroll
        for (int q = 0; q < 64; ++q) acc += TsT[q][p] * Ws[sub][q];
        WcT[(size_t)n * 512 + h * 64 + p] = f2bf(acc);
        __syncthreads();
    }
}

// ---------------------------------------------------------------------------
// Kernel 4: out(32768x768) = Q_addr(32768x512) @ Wc(512x768), bf16 MFMA.
// 128x128 block tile, BK=64 (one head per K-step), 4 waves, 4x4 MFMA tiles.
// A from preconverted bf16 Qbf (QBF=true) or fp32 Q fallback.
// ---------------------------------------------------------------------------
template <bool QBF>
__global__ __launch_bounds__(256, 2) void matmul_kernel(
    const float* __restrict__ Qf, const unsigned short* __restrict__ Qb,
    const unsigned short* __restrict__ WcT, float* __restrict__ out) {
    const int mTile = blockIdx.x;  // 0..255
    const int nTile = blockIdx.y;  // 0..5
    const int t = threadIdx.x;
    const int wave = t >> 6, lane = t & 63;
    const int wm = wave >> 1, wn = wave & 1;
    const int quad = lane >> 4, l15 = lane & 15;
    __shared__ __align__(16) unsigned short As[128][72];
    __shared__ __align__(16) unsigned short Bs[128][72];
    const int b = mTile >> 5;
    const int s0 = (mTile & 31) * 128;
    const int nBase = nTile * 128;
    f32x4_t acc[4][4] = {};

    for (int h = 0; h < 8; ++h) {
        const size_t bh = (size_t)(b * H_ + h);
        if (QBF) {
            const unsigned short* Qbh = Qb + bh * S_ * D_;
            #pragma unroll
            for (int i = 0; i < 4; ++i) {
                int f = i * 256 + t;
                int row = f >> 3, c8 = f & 7;
                int s = s0 + row;
                uint4 u = make_uint4(0, 0, 0, 0);
                if (s > 0) u = *(const uint4*)(Qbh + (size_t)(s - 1) * D_ + c8 * 8);
                *(uint4*)(&As[row][c8 * 8]) = u;
            }
        } else {
            const float* Qbh = Qf + bh * S_ * D_;
            #pragma unroll
            for (int i = 0; i < 8; ++i) {
                int f = i * 256 + t;
                int row = f >> 4, c4 = f & 15;
                int s = s0 + row;
                float4 q4 = make_float4(0.f, 0.f, 0.f, 0.f);
                if (s > 0) q4 = *(const float4*)(Qbh + (size_t)(s - 1) * D_ + c4 * 4);
                ushort4 u;
                u.x = f2bf(q4.x); u.y = f2bf(q4.y); u.z = f2bf(q4.z); u.w = f2bf(q4.w);
                *(ushort4*)(&As[row][c4 * 4]) = u;
            }
        }
        #pragma unroll
        for (int i = 0; i < 4; ++i) {
            int f = i * 256 + t;
            int row = f >> 3, c8 = f & 7;
            uint4 w = *(const uint4*)(WcT + (size_t)(nBase + row) * 512 + h * 64 + c8 * 8);
            *(uint4*)(&Bs[row][c8 * 8]) = w;
        }
        __syncthreads();
        #pragma unroll
        for (int c = 0; c < 2; ++c) {
            int k0 = c * 32 + quad * 8;
            bfrag_t af[4], bf[4];
            #pragma unroll
            for (int i = 0; i < 4; ++i)
                af[i] = *(const bfrag_t*)(&As[wm * 64 + i * 16 + l15][k0]);
            #pragma unroll
            for (int j = 0; j < 4; ++j)
                bf[j] = *(const bfrag_t*)(&Bs[wn * 64 + j * 16 + l15][k0]);
            #pragma unroll
            for (int i = 0; i < 4; ++i)
                #pragma unroll
                for (int j = 0; j < 4; ++j)
                    acc[i][j] = __builtin_amdgcn_mfma_f32_16x16x32_bf16(af[i], bf[j], acc[i][j], 0, 0, 0);
        }
        __syncthreads();
    }
    const size_t mBase = (size_t)mTile * 128;
    #pragma unroll
    for (int i = 0; i < 4; ++i) {
        int mrow = wm * 64 + i * 16 + quad * 4;
        #pragma unroll
        for (int j = 0; j < 4; ++j) {
            int n = nBase + wn * 64 + j * 16 + l15;
            #pragma unroll
            for (int r = 0; r < 4; ++r)
                out[(mBase + mrow + r) * DM_ + n] = acc[i][j][r];
        }
    }
}

// ---------------------------------------------------------------------------
extern "C" void kernel_launch(void* const* d_in, const int* in_sizes, int n_in,
                              void* d_out, int out_size, void* d_ws, size_t ws_size,
                              hipStream_t stream) {
    const float* Q     = (const float*)d_in[0];
    const float* V     = (const float*)d_in[1];
    const float* trace = (const float*)d_in[2];
    const float* Wout  = (const float*)d_in[3];
    float* out = (float*)d_out;

    float* gG   = (float*)d_ws;                             // 32768 f
    float* gU   = gG + 32768;                               // 32768 f
    float* Tnew = gU + 32768;                               // 32768 f
    unsigned short* WcT = (unsigned short*)(Tnew + 32768);  // 768*512 bf16
    unsigned short* Qbf = WcT + 393216;                     // 8*8*4096*64 bf16

    const size_t qbf_bytes = (size_t)B_ * H_ * S_ * D_ * 2;
    const size_t base_bytes = 3u * 32768u * 4u + 393216u * 2u;
    const int useQbf = (ws_size >= base_bytes + qbf_bytes) ? 1 : 0;

    hipMemsetAsync(d_ws, 0, 2 * 32768 * sizeof(float), stream);
    gram_kernel<<<dim3(8, 8, 8), 256, 0, stream>>>(Q, V, gG, gU, Qbf, useQbf);
    trace_kernel<<<8, 256, 0, stream>>>(gG, gU, trace, Tnew);
    wc_kernel<<<dim3(6, 8), 256, 0, stream>>>(Tnew, Wout, WcT);
    if (useQbf)
        matmul_kernel<true><<<dim3(256, 6), 256, 0, stream>>>(Q, Qbf, WcT, out);
    else
        matmul_kernel<false><<<dim3(256, 6), 256, 0, stream>>>(Q, Qbf, WcT, out);
}

// Round 3
// 266.561 us; speedup vs baseline: 1.3669x; 1.1491x over previous
//
#include <hip/hip_runtime.h>

#define B_ 8
#define H_ 8
#define S_ 4096
#define D_ 64
#define DM_ 768
#define NSTORE 4094            // S-2
#define DENOM 32752.0f         // B*(S-2)

typedef short bfrag_t __attribute__((ext_vector_type(8)));   // 8 bf16 (A/B frag)
typedef float f32x4_t __attribute__((ext_vector_type(4)));   // C/D frag

__device__ inline unsigned short f2bf(float x) {
    unsigned int u = __float_as_uint(x);
    unsigned int r = (u + 0x7fffu + ((u >> 16) & 1u)) >> 16;  // RNE
    return (unsigned short)r;
}

__device__ inline void async_copy16(const void* g, void* lds) {
    __builtin_amdgcn_global_load_lds((__attribute__((address_space(1))) void*)g,
                                     (__attribute__((address_space(3))) void*)lds,
                                     16, 0, 0);
}

#define MFMA16(a, b, c) __builtin_amdgcn_mfma_f32_16x16x32_bf16((a), (b), (c), 0, 0, 0)

// ---------------------------------------------------------------------------
// Kernel 1: per-head G = Qn^T Q, U = Q^T V (64x64, K = rows).
// grid (split, h=8, b=8), block 256 (4 waves). No fp32 LDS: row norm via
// shfl at load, bf16 convert in-register, scatter into swizzled transposed
// LDS (granule g stored at g ^ ((p>>2)&7)). PART: partial slabs; else atomics.
// Also emits bf16 copy of Q (Qbf) for the output GEMM.
// ---------------------------------------------------------------------------
template <bool PART>
__global__ __launch_bounds__(256, 4) void gram_kernel(
    const float* __restrict__ Q, const float* __restrict__ V,
    float* __restrict__ gG, float* __restrict__ gU,
    unsigned short* __restrict__ Qbf, float* __restrict__ gP, int writeQbf) {
    const int split = blockIdx.x, h = blockIdx.y, b = blockIdx.z;
    const int nsplit = gridDim.x;
    const int rowsPer = 4096 / nsplit;
    const int nTiles = rowsPer >> 6;
    const int t = threadIdx.x;
    const int wave = t >> 6, lane = t & 63;
    const int quad = lane >> 4, l15 = lane & 15;
    __shared__ __align__(16) unsigned short QT[64 * 64];
    __shared__ __align__(16) unsigned short QnT[64 * 64];
    __shared__ __align__(16) unsigned short VT[64 * 64];

    const size_t bh = (size_t)(b * H_ + h);
    const float* Qbh = Q + bh * S_ * D_;
    const float* Vbh = V + bh * S_ * D_;
    unsigned short* Qo = Qbf + bh * S_ * D_;

    f32x4_t accG[4] = {}, accU[4] = {};
    const int r0 = split * rowsPer;

    for (int tile = 0; tile < nTiles; ++tile) {
        const int rbase = r0 + tile * 64;
        #pragma unroll
        for (int i = 0; i < 4; ++i) {
            int f = i * 256 + t;
            int rowl = f >> 4, c4 = f & 15;
            int r = rbase + rowl;
            float4 q4 = *(const float4*)(Qbh + (size_t)r * D_ + c4 * 4);
            if (writeQbf) {
                ushort4 u;
                u.x = f2bf(q4.x); u.y = f2bf(q4.y); u.z = f2bf(q4.z); u.w = f2bf(q4.w);
                *(ushort4*)(Qo + (size_t)r * D_ + c4 * 4) = u;
            }
            float4 v4 = make_float4(0.f, 0.f, 0.f, 0.f);
            if (r < NSTORE) v4 = *(const float4*)(Vbh + (size_t)(r + 2) * D_ + c4 * 4);
            else q4 = make_float4(0.f, 0.f, 0.f, 0.f);
            // full row norm via 16-lane shuffle reduce (each row owned by 16 lanes)
            float ss = q4.x * q4.x + q4.y * q4.y + q4.z * q4.z + q4.w * q4.w;
            ss += __shfl_xor(ss, 1);
            ss += __shfl_xor(ss, 2);
            ss += __shfl_xor(ss, 4);
            ss += __shfl_xor(ss, 8);
            float sc = 1.0f / fmaxf(ss, 1e-16f);   // 1/clip(norm,eps)^2
            int col = rowl ^ ((c4 & 7) << 3);      // swizzle key e=(p>>2)&7 = c4&7
            float qa[4] = {q4.x, q4.y, q4.z, q4.w};
            float va[4] = {v4.x, v4.y, v4.z, v4.w};
            #pragma unroll
            for (int j = 0; j < 4; ++j) {
                int p = c4 * 4 + j;
                QT [p * 64 + col] = f2bf(qa[j]);
                QnT[p * 64 + col] = f2bf(qa[j] * sc);
                VT [p * 64 + col] = f2bf(va[j]);
            }
        }
        __syncthreads();
        #pragma unroll
        for (int c = 0; c < 2; ++c) {
            int pA = wave * 16 + l15;
            int offA = pA * 64 + (((c * 4 + quad) ^ ((pA >> 2) & 7)) << 3);
            bfrag_t ag = *(const bfrag_t*)&QnT[offA];
            bfrag_t au = *(const bfrag_t*)&QT[offA];
            #pragma unroll
            for (int j = 0; j < 4; ++j) {
                int pB = j * 16 + l15;
                int offB = pB * 64 + (((c * 4 + quad) ^ ((pB >> 2) & 7)) << 3);
                bfrag_t bq = *(const bfrag_t*)&QT[offB];
                bfrag_t bv = *(const bfrag_t*)&VT[offB];
                accG[j] = MFMA16(ag, bq, accG[j]);
                accU[j] = MFMA16(au, bv, accU[j]);
            }
        }
        __syncthreads();
    }
    // C layout: col = j*16+l15, row = wave*16 + quad*4 + r
    if (PART) {
        const int slab = split * 8 + b;                  // 0..127
        float* base = gP + ((size_t)(h * 128 + slab) * 2) * 4096;
        #pragma unroll
        for (int j = 0; j < 4; ++j) {
            int coln = j * 16 + l15;
            #pragma unroll
            for (int r = 0; r < 4; ++r) {
                int row = wave * 16 + quad * 4 + r;
                base[row * 64 + coln]        = accG[j][r];
                base[4096 + row * 64 + coln] = accU[j][r];
            }
        }
    } else {
        float* gGh = gG + h * 4096;
        float* gUh = gU + h * 4096;
        #pragma unroll
        for (int j = 0; j < 4; ++j) {
            int coln = j * 16 + l15;
            #pragma unroll
            for (int r = 0; r < 4; ++r) {
                int row = wave * 16 + quad * 4 + r;
                atomicAdd(&gGh[row * 64 + coln], accG[j][r]);
                atomicAdd(&gUh[row * 64 + coln], accU[j][r]);
            }
        }
    }
}

// ---------------------------------------------------------------------------
// Kernel 1b: sum 128 partial slabs -> gG/gU. grid (8 h, 32 chunks), block 256.
// ---------------------------------------------------------------------------
__global__ __launch_bounds__(256) void reduce_kernel(
    const float* __restrict__ gP, float* __restrict__ gG, float* __restrict__ gU) {
    const int h = blockIdx.x, chunk = blockIdx.y, t = threadIdx.x;
    const int arr = t >> 7, idx = chunk * 128 + (t & 127);
    const float* base = gP + ((size_t)(h * 128) * 2 + arr) * 4096 + idx;
    float s = 0.f;
    #pragma unroll 8
    for (int sl = 0; sl < 128; ++sl) s += base[(size_t)sl * 2 * 4096];
    (arr ? gU : gG)[h * 4096 + idx] = s;
}

// ---------------------------------------------------------------------------
// Kernel 2: T_new[h] = 0.99*(trace - G@trace/denom) + 0.1*U/denom. grid=8.
// float4 microtile: thread owns (p, 16 q).
// ---------------------------------------------------------------------------
__global__ __launch_bounds__(256) void trace_kernel(
    const float* __restrict__ gG, const float* __restrict__ gU,
    const float* __restrict__ trace, float* __restrict__ Tnew) {
    const int h = blockIdx.x, t = threadIdx.x;
    __shared__ float Gs[64][68];
    __shared__ float Ts[64][68];
    const float* Gh = gG + h * 4096;
    const float* Uh = gU + h * 4096;
    const float* Th = trace + h * 4096;
    float* To = Tnew + h * 4096;
    for (int k = 0; k < 16; ++k) {
        int e = k * 256 + t;
        Gs[e >> 6][e & 63] = Gh[e];
        Ts[e >> 6][e & 63] = Th[e];
    }
    __syncthreads();
    const int p = t >> 2, q0 = (t & 3) * 16;
    f32x4_t acc[4] = {};
    for (int r = 0; r < 64; ++r) {
        float g = Gs[p][r];
        #pragma unroll
        for (int i = 0; i < 4; ++i) {
            f32x4_t tv = *(const f32x4_t*)&Ts[r][q0 + i * 4];
            acc[i] += g * tv;
        }
    }
    const float inv = 1.0f / DENOM;
    #pragma unroll
    for (int i = 0; i < 4; ++i) {
        int e = p * 64 + q0 + i * 4;
        f32x4_t ts = *(const f32x4_t*)&Ts[p][q0 + i * 4];
        f32x4_t uu = *(const f32x4_t*)(Uh + e);
        f32x4_t res = 0.99f * (ts - acc[i] * inv) + (0.1f * inv) * uu;
        *(f32x4_t*)(To + e) = res;
    }
}

// ---------------------------------------------------------------------------
// Kernel 3: WcT[n][h*64+p] = sum_q T_new[h][p][q] * W_out[n][h*64+q], bf16.
// grid (6 nc, 8 h). One barrier; thread computes 8n x 4p tile via float4.
// ---------------------------------------------------------------------------
__global__ __launch_bounds__(256) void wc_kernel(
    const float* __restrict__ Tnew, const float* __restrict__ Wout,
    unsigned short* __restrict__ WcT) {
    const int nc = blockIdx.x, h = blockIdx.y, t = threadIdx.x;
    __shared__ float TsT[64][68];    // [q][p]
    __shared__ float WbT[64][132];   // [q][n]
    const float* Th = Tnew + h * 4096;
    #pragma unroll
    for (int i = 0; i < 4; ++i) {
        int f = i * 256 + t;
        int p = f >> 4, q4 = f & 15;
        float4 v = *(const float4*)(Th + p * 64 + q4 * 4);
        TsT[q4 * 4 + 0][p] = v.x; TsT[q4 * 4 + 1][p] = v.y;
        TsT[q4 * 4 + 2][p] = v.z; TsT[q4 * 4 + 3][p] = v.w;
    }
    #pragma unroll
    for (int i = 0; i < 8; ++i) {
        int f = i * 256 + t;
        int n = f >> 4, q4 = f & 15;
        float4 w = *(const float4*)(Wout + (size_t)(nc * 128 + n) * 512 + h * 64 + q4 * 4);
        WbT[q4 * 4 + 0][n] = w.x; WbT[q4 * 4 + 1][n] = w.y;
        WbT[q4 * 4 + 2][n] = w.z; WbT[q4 * 4 + 3][n] = w.w;
    }
    __syncthreads();
    const int n0 = (t >> 4) * 8, p0 = (t & 15) * 4;
    f32x4_t acc[8] = {};
    for (int q = 0; q < 64; ++q) {
        f32x4_t tp = *(const f32x4_t*)&TsT[q][p0];
        f32x4_t w0 = *(const f32x4_t*)&WbT[q][n0];
        f32x4_t w1 = *(const f32x4_t*)&WbT[q][n0 + 4];
        #pragma unroll
        for (int i = 0; i < 4; ++i) acc[i] += w0[i] * tp;
        #pragma unroll
        for (int i = 0; i < 4; ++i) acc[4 + i] += w1[i] * tp;
    }
    #pragma unroll
    for (int i = 0; i < 8; ++i) {
        int n = nc * 128 + n0 + i;
        ushort4 u;
        u.x = f2bf(acc[i][0]); u.y = f2bf(acc[i][1]);
        u.z = f2bf(acc[i][2]); u.w = f2bf(acc[i][3]);
        *(ushort4*)(WcT + (size_t)n * 512 + h * 64 + p0) = u;
    }
}

// ---------------------------------------------------------------------------
// Kernel 4: out(32768x768) = Q_addr(32768x512) @ Wc(512x768), bf16 MFMA.
// 128x128 tile, BK=64, global_load_lds width=16 into swizzled [128][64]
// (granule g stored at g ^ (row&7) -> conflict-free b128 frag reads).
// ---------------------------------------------------------------------------
__global__ __launch_bounds__(256, 3) void matmul_fast(
    const unsigned short* __restrict__ Qb, const unsigned short* __restrict__ WcT,
    float* __restrict__ out) {
    const int mTile = blockIdx.x;  // 0..255
    const int nTile = blockIdx.y;  // 0..5
    const int t = threadIdx.x;
    const int wave = t >> 6, lane = t & 63;
    const int wm = wave >> 1, wn = wave & 1;
    const int quad = lane >> 4, l15 = lane & 15;
    __shared__ __align__(16) unsigned short As[128 * 64];
    __shared__ __align__(16) unsigned short Bs[128 * 64];
    const int b = mTile >> 5;
    const int s0 = (mTile & 31) * 128;
    const int nBase = nTile * 128;
    const int rl8 = lane >> 3, g = lane & 7;
    const int gs = g ^ rl8;                    // swizzled source granule
    f32x4_t acc[4][4] = {};

    for (int h = 0; h < 8; ++h) {
        const unsigned short* Qbh = Qb + (size_t)(b * H_ + h) * S_ * D_;
        #pragma unroll
        for (int k = 0; k < 4; ++k) {
            int ch = wave * 4 + k;             // chunk 0..15 (8 rows each)
            int row = ch * 8 + rl8;
            int s = s0 + row;
            int sc = (s > 0) ? (s - 1) : 0;
            async_copy16(Qbh + (size_t)sc * 64 + gs * 8, &As[ch * 512 + lane * 8]);
            async_copy16(WcT + (size_t)(nBase + row) * 512 + h * 64 + gs * 8,
                         &Bs[ch * 512 + lane * 8]);
        }
        __syncthreads();
        if (s0 == 0) {                          // block-uniform: zero A row 0 (s-1 = -1)
            if (t < 8) ((uint4*)As)[t] = make_uint4(0, 0, 0, 0);
            __syncthreads();
        }
        #pragma unroll
        for (int c = 0; c < 2; ++c) {
            int gk = c * 4 + quad;
            bfrag_t af[4], bf[4];
            #pragma unroll
            for (int i = 0; i < 4; ++i) {
                int row = wm * 64 + i * 16 + l15;
                af[i] = *(const bfrag_t*)&As[row * 64 + ((gk ^ (row & 7)) << 3)];
            }
            #pragma unroll
            for (int j = 0; j < 4; ++j) {
                int row = wn * 64 + j * 16 + l15;
                bf[j] = *(const bfrag_t*)&Bs[row * 64 + ((gk ^ (row & 7)) << 3)];
            }
            #pragma unroll
            for (int i = 0; i < 4; ++i)
                #pragma unroll
                for (int j = 0; j < 4; ++j)
                    acc[i][j] = MFMA16(af[i], bf[j], acc[i][j]);
        }
        __syncthreads();
    }
    const size_t mBase = (size_t)mTile * 128;
    #pragma unroll
    for (int i = 0; i < 4; ++i) {
        int mrow = wm * 64 + i * 16 + quad * 4;
        #pragma unroll
        for (int j = 0; j < 4; ++j) {
            int n = nBase + wn * 64 + j * 16 + l15;
            #pragma unroll
            for (int r = 0; r < 4; ++r)
                out[(mBase + mrow + r) * DM_ + n] = acc[i][j][r];
        }
    }
}

// Fallback GEMM reading fp32 Q (used only if ws can't hold Qbf).
__global__ __launch_bounds__(256, 2) void matmul_f32(
    const float* __restrict__ Qf, const unsigned short* __restrict__ WcT,
    float* __restrict__ out) {
    const int mTile = blockIdx.x, nTile = blockIdx.y;
    const int t = threadIdx.x;
    const int wave = t >> 6, lane = t & 63;
    const int wm = wave >> 1, wn = wave & 1;
    const int quad = lane >> 4, l15 = lane & 15;
    __shared__ __align__(16) unsigned short As[128][72];
    __shared__ __align__(16) unsigned short Bs[128][72];
    const int b = mTile >> 5;
    const int s0 = (mTile & 31) * 128;
    const int nBase = nTile * 128;
    f32x4_t acc[4][4] = {};
    for (int h = 0; h < 8; ++h) {
        const float* Qbh = Qf + (size_t)(b * H_ + h) * S_ * D_;
        #pragma unroll
        for (int i = 0; i < 8; ++i) {
            int f = i * 256 + t;
            int row = f >> 4, c4 = f & 15;
            int s = s0 + row;
            float4 q4 = make_float4(0.f, 0.f, 0.f, 0.f);
            if (s > 0) q4 = *(const float4*)(Qbh + (size_t)(s - 1) * D_ + c4 * 4);
            ushort4 u;
            u.x = f2bf(q4.x); u.y = f2bf(q4.y); u.z = f2bf(q4.z); u.w = f2bf(q4.w);
            *(ushort4*)(&As[row][c4 * 4]) = u;
        }
        #pragma unroll
        for (int i = 0; i < 4; ++i) {
            int f = i * 256 + t;
            int row = f >> 3, c8 = f & 7;
            uint4 w = *(const uint4*)(WcT + (size_t)(nBase + row) * 512 + h * 64 + c8 * 8);
            *(uint4*)(&Bs[row][c8 * 8]) = w;
        }
        __syncthreads();
        #pragma unroll
        for (int c = 0; c < 2; ++c) {
            int k0 = c * 32 + quad * 8;
            bfrag_t af[4], bf[4];
            #pragma unroll
            for (int i = 0; i < 4; ++i)
                af[i] = *(const bfrag_t*)(&As[wm * 64 + i * 16 + l15][k0]);
            #pragma unroll
            for (int j = 0; j < 4; ++j)
                bf[j] = *(const bfrag_t*)(&Bs[wn * 64 + j * 16 + l15][k0]);
            #pragma unroll
            for (int i = 0; i < 4; ++i)
                #pragma unroll
                for (int j = 0; j < 4; ++j)
                    acc[i][j] = MFMA16(af[i], bf[j], acc[i][j]);
        }
        __syncthreads();
    }
    const size_t mBase = (size_t)mTile * 128;
    #pragma unroll
    for (int i = 0; i < 4; ++i) {
        int mrow = wm * 64 + i * 16 + quad * 4;
        #pragma unroll
        for (int j = 0; j < 4; ++j) {
            int n = nBase + wn * 64 + j * 16 + l15;
            #pragma unroll
            for (int r = 0; r < 4; ++r)
                out[(mBase + mrow + r) * DM_ + n] = acc[i][j][r];
        }
    }
}

// ---------------------------------------------------------------------------
extern "C" void kernel_launch(void* const* d_in, const int* in_sizes, int n_in,
                              void* d_out, int out_size, void* d_ws, size_t ws_size,
                              hipStream_t stream) {
    const float* Q     = (const float*)d_in[0];
    const float* V     = (const float*)d_in[1];
    const float* trace = (const float*)d_in[2];
    const float* Wout  = (const float*)d_in[3];
    float* out = (float*)d_out;

    // ws layout
    float* gG   = (float*)d_ws;                                      // @0       128 KB
    float* gU   = gG + 32768;                                        // @128K    128 KB
    float* Tnew = gU + 32768;                                        // @256K    128 KB
    unsigned short* WcT = (unsigned short*)(Tnew + 32768);           // @384K    768 KB
    unsigned short* Qbf = WcT + 393216;                              // @1152K   32 MB
    float* gP = (float*)(Qbf + (size_t)B_ * H_ * S_ * D_);           // @33.1M   32 MB

    const size_t needQbf  = 1179648u + 33554432u;
    const size_t needFull = needQbf + 33554432u;
    const int mode = (ws_size >= needFull) ? 2 : ((ws_size >= needQbf) ? 1 : 0);

    if (mode == 2) {
        gram_kernel<true><<<dim3(16, 8, 8), 256, 0, stream>>>(Q, V, gG, gU, Qbf, gP, 1);
        reduce_kernel<<<dim3(8, 32), 256, 0, stream>>>(gP, gG, gU);
    } else {
        hipMemsetAsync(d_ws, 0, 2 * 32768 * sizeof(float), stream);
        gram_kernel<false><<<dim3(8, 8, 8), 256, 0, stream>>>(Q, V, gG, gU, Qbf, gP, mode >= 1);
    }
    trace_kernel<<<8, 256, 0, stream>>>(gG, gU, trace, Tnew);
    wc_kernel<<<dim3(6, 8), 256, 0, stream>>>(Tnew, Wout, WcT);
    if (mode >= 1)
        matmul_fast<<<dim3(256, 6), 256, 0, stream>>>(Qbf, WcT, out);
    else
        matmul_f32<<<dim3(256, 6), 256, 0, stream>>>(Q, WcT, out);
}